// Round 1
// baseline (99.475 us; speedup 1.0000x reference)
//
#include <hip/hip_runtime.h>
#include <stdint.h>

#define NN 2048
#define MM 2048
#define DJ 16
#define DM 16
#define DG 8
#define HID 64
#define NCHUNK 16

typedef _Float16 half2_t __attribute__((ext_vector_type(2)));

__device__ __forceinline__ half2_t hrelu2(half2_t t) {
    half2_t z = {(_Float16)0.f, (_Float16)0.f};
#if __has_builtin(__builtin_elementwise_max)
    return __builtin_elementwise_max(t, z);   // v_pk_max_f16
#else
    half2_t r;
    r.x = t.x > (_Float16)0.f ? t.x : (_Float16)0.f;
    r.y = t.y > (_Float16)0.f ? t.y : (_Float16)0.f;
    return r;
#endif
}

#if __has_builtin(__builtin_amdgcn_fdot2)
#define FDOT2(a, b, c) __builtin_amdgcn_fdot2((a), (b), (c), false)  // v_dot2_f32_f16
#else
#define FDOT2(a, b, c) fmaf((float)(a).y, (float)(b).y, fmaf((float)(a).x, (float)(b).x, (c)))
#endif

// Kernel 1: A[n][h] = hj[n,h];  B[m][h] = hm[m,h] + hg[h] (b1 folded);  w2h = fp16(W2)
__global__ __launch_bounds__(256) void precompute_kernel(
    const float* __restrict__ job, const float* __restrict__ mac,
    const float* __restrict__ gv,
    const float* __restrict__ Wj, const float* __restrict__ bj,
    const float* __restrict__ Wm, const float* __restrict__ bm,
    const float* __restrict__ Wg, const float* __restrict__ bg,
    const float* __restrict__ W1, const float* __restrict__ b1,
    const float* __restrict__ W2,
    _Float16* __restrict__ A, _Float16* __restrict__ B, _Float16* __restrict__ w2h)
{
    const int tid = threadIdx.x;
    const int idx = blockIdx.x * 256 + tid;
    if (blockIdx.x == 0 && tid < HID) w2h[tid] = (_Float16)W2[tid];
    if (idx < NN * HID) {
        const int n = idx >> 6, h = idx & 63;
        const float x = job[n];
        float s = 0.f;
#pragma unroll
        for (int d = 0; d < DJ; ++d) {
            float jf = fmaxf(fmaf(x, Wj[d], bj[d]), 0.f);
            s = fmaf(jf, W1[d * HID + h], s);
        }
        A[idx] = (_Float16)s;
    } else {
        const int i2 = idx - NN * HID;
        if (i2 < MM * HID) {
            const int m = i2 >> 6, h = i2 & 63;
            const float x = mac[m];
            float s = b1[h];
#pragma unroll
            for (int d = 0; d < DM; ++d) {
                float mf = fmaxf(fmaf(x, Wm[d], bm[d]), 0.f);
                s = fmaf(mf, W1[(DJ + d) * HID + h], s);
            }
#pragma unroll
            for (int d = 0; d < DG; ++d) {
                float g = bg[d];
#pragma unroll
                for (int e = 0; e < DG; ++e) g = fmaf(gv[e], Wg[e * DG + d], g);
                g = fmaxf(g, 0.f);
                s = fmaf(g, W1[(DJ + DM + d) * HID + h], s);
            }
            B[i2] = (_Float16)s;
        }
    }
}

// Kernel 2: Q[n,m] = b2 + sum_h relu(A[n,h] + B[m,h]) * w2[h]
// block = 256 threads = 256 consecutive m; NCHUNK n-rows staged in LDS (broadcast reads).
__global__ __launch_bounds__(256, 2) void qmat_kernel(
    const _Float16* __restrict__ A, const _Float16* __restrict__ B,
    const _Float16* __restrict__ w2h, const float* __restrict__ b2p,
    float* __restrict__ out)
{
    __shared__ __align__(16) _Float16 lA[NCHUNK * HID];   // 2 KB
    const int tid = threadIdx.x;
    const int m = blockIdx.x * 256 + tid;
    const int n0 = blockIdx.y * NCHUNK;

    // stage A n-chunk into LDS: 16 rows * 128 B = 128 uint4
    if (tid < (NCHUNK * HID * 2) / 16) {
        ((uint4*)lA)[tid] = ((const uint4*)(A + (size_t)n0 * HID))[tid];
    }

    // per-thread B row -> 32 half2 registers
    const uint4* bv = (const uint4*)(B + (size_t)m * HID);
    half2_t breg[32];
#pragma unroll
    for (int i = 0; i < 8; ++i) {
        uint4 r = bv[i];
        breg[4 * i + 0] = __builtin_bit_cast(half2_t, r.x);
        breg[4 * i + 1] = __builtin_bit_cast(half2_t, r.y);
        breg[4 * i + 2] = __builtin_bit_cast(half2_t, r.z);
        breg[4 * i + 3] = __builtin_bit_cast(half2_t, r.w);
    }
    // w2 (uniform -> scalar loads)
    const uint32_t* w2u = (const uint32_t*)w2h;
    half2_t w2r[32];
#pragma unroll
    for (int k = 0; k < 32; ++k) w2r[k] = __builtin_bit_cast(half2_t, w2u[k]);
    const float b2 = b2p[0];

    __syncthreads();

    float* orow = out + (size_t)n0 * MM + m;
    for (int ni = 0; ni < NCHUNK; ni += 2) {
        const uint4* la0 = (const uint4*)(lA + (ni + 0) * HID);
        const uint4* la1 = (const uint4*)(lA + (ni + 1) * HID);
        float acc0a = 0.f, acc0b = 0.f, acc1a = 0.f, acc1b = 0.f;
#pragma unroll
        for (int kk = 0; kk < 8; ++kk) {
            const uint4 a0v = la0[kk];   // ds_read_b128, all lanes same addr (broadcast)
            const uint4 a1v = la1[kk];
            const int kb = 4 * kk;
            half2_t t;
            t = __builtin_bit_cast(half2_t, a0v.x) + breg[kb + 0]; t = hrelu2(t); acc0a = FDOT2(t, w2r[kb + 0], acc0a);
            t = __builtin_bit_cast(half2_t, a0v.y) + breg[kb + 1]; t = hrelu2(t); acc0b = FDOT2(t, w2r[kb + 1], acc0b);
            t = __builtin_bit_cast(half2_t, a0v.z) + breg[kb + 2]; t = hrelu2(t); acc0a = FDOT2(t, w2r[kb + 2], acc0a);
            t = __builtin_bit_cast(half2_t, a0v.w) + breg[kb + 3]; t = hrelu2(t); acc0b = FDOT2(t, w2r[kb + 3], acc0b);
            t = __builtin_bit_cast(half2_t, a1v.x) + breg[kb + 0]; t = hrelu2(t); acc1a = FDOT2(t, w2r[kb + 0], acc1a);
            t = __builtin_bit_cast(half2_t, a1v.y) + breg[kb + 1]; t = hrelu2(t); acc1b = FDOT2(t, w2r[kb + 1], acc1b);
            t = __builtin_bit_cast(half2_t, a1v.z) + breg[kb + 2]; t = hrelu2(t); acc1a = FDOT2(t, w2r[kb + 2], acc1a);
            t = __builtin_bit_cast(half2_t, a1v.w) + breg[kb + 3]; t = hrelu2(t); acc1b = FDOT2(t, w2r[kb + 3], acc1b);
        }
        orow[(size_t)(ni + 0) * MM] = acc0a + acc0b + b2;
        orow[(size_t)(ni + 1) * MM] = acc1a + acc1b + b2;
    }
}

extern "C" void kernel_launch(void* const* d_in, const int* in_sizes, int n_in,
                              void* d_out, int out_size, void* d_ws, size_t ws_size,
                              hipStream_t stream) {
    const float* job = (const float*)d_in[0];
    const float* mac = (const float*)d_in[1];
    const float* gv  = (const float*)d_in[2];
    const float* Wj  = (const float*)d_in[3];
    const float* bj  = (const float*)d_in[4];
    const float* Wm  = (const float*)d_in[5];
    const float* bm  = (const float*)d_in[6];
    const float* Wg  = (const float*)d_in[7];
    const float* bg  = (const float*)d_in[8];
    const float* W1  = (const float*)d_in[9];
    const float* b1  = (const float*)d_in[10];
    const float* W2  = (const float*)d_in[11];
    const float* b2  = (const float*)d_in[12];

    _Float16* A   = (_Float16*)d_ws;                 // 256 KB
    _Float16* Bp  = A + (size_t)NN * HID;            // 256 KB
    _Float16* w2h = Bp + (size_t)MM * HID;           // 128 B

    precompute_kernel<<<(2 * NN * HID) / 256, 256, 0, stream>>>(
        job, mac, gv, Wj, bj, Wm, bm, Wg, bg, W1, b1, W2, A, Bp, w2h);

    dim3 grid(MM / 256, NN / NCHUNK);   // (8, 128) = 1024 blocks
    qmat_kernel<<<grid, 256, 0, stream>>>(A, Bp, w2h, b2, (float*)d_out);
}